// Round 8
// baseline (18.694 us; speedup 1.0000x reference)
//
#include <hip/hip_runtime.h>
#include <hip/hip_bf16.h>
#include <math.h>

#define DD 64  // feature dim

typedef __bf16 bf16x8 __attribute__((ext_vector_type(8)));
typedef float f32x4 __attribute__((ext_vector_type(4)));

// Convert 8 fp32 -> bf16 fragment, accumulating sum of squares of the
// bf16-ROUNDED values into s (so d^2 = nx+ny-2dot = ||xb-yb||^2 >= 0).
__device__ inline bf16x8 cvt8n(const float4 a, const float4 b, float& s) {
  bf16x8 r;
  float t;
  r[0] = (__bf16)a.x; t = (float)r[0]; s = fmaf(t, t, s);
  r[1] = (__bf16)a.y; t = (float)r[1]; s = fmaf(t, t, s);
  r[2] = (__bf16)a.z; t = (float)r[2]; s = fmaf(t, t, s);
  r[3] = (__bf16)a.w; t = (float)r[3]; s = fmaf(t, t, s);
  r[4] = (__bf16)b.x; t = (float)r[4]; s = fmaf(t, t, s);
  r[5] = (__bf16)b.y; t = (float)r[5]; s = fmaf(t, t, s);
  r[6] = (__bf16)b.z; t = (float)r[6]; s = fmaf(t, t, s);
  r[7] = (__bf16)b.w; t = (float)r[7]; s = fmaf(t, t, s);
  return r;
}

// Fully fused CDist, no LDS, no __syncthreads, single phase:
//   out[i][j] = sqrt(max(||xb_i||^2 + ||yb_j||^2 - 2 xb_i.yb_j, 0))
// Each wave owns a 16x32 output tile (i x j) -> 8192 waves = up to 8/SIMD
// (R4 was 4/SIMD grid-capped; R5's regression was the forced 64-VGPR clamp,
// not the tile shape -- no min-waves bound here, let VGPRs land naturally).
// Swapped-operand MFMA (y as A, x as B): C/D row->j, col->i, so each lane's
// 4 acc regs are 4 consecutive j -> one nontemporal float4 store per frag.
__global__ __launch_bounds__(256) void cdist_fused(
    const float* __restrict__ x, const float* __restrict__ y,
    float* __restrict__ out, int N, int M) {
  const int lane = threadIdx.x & 63;
  const int wid  = threadIdx.x >> 6;         // 0..3
  const int wr = wid >> 1, wc = wid & 1;     // 2x2 wave grid
  const int i0 = blockIdx.y * 32 + wr * 16;  // wave's x-row base (16 rows)
  const int j0 = blockIdx.x * 64 + wc * 32;  // wave's y-row base (32 rows)
  const int lrow = lane & 15;
  const int kgrp = lane >> 4;

  // Fragment loads (fp32 global -> bf16 regs) + partial norms.
  // A/B layout: lane l holds 8 contiguous k-elems of row (l&15) at k-offset
  // (l>>4)*8 (+32 per k-step). Verified rounds 2-7.
  bf16x8 a[2], b[2][2];
  float sa = 0.f, sb[2] = {0.f, 0.f};
  {
    const float* px = &x[(size_t)(i0 + lrow) * DD + kgrp * 8];
    a[0] = cvt8n(*reinterpret_cast<const float4*>(px),
                 *reinterpret_cast<const float4*>(px + 4), sa);
    a[1] = cvt8n(*reinterpret_cast<const float4*>(px + 32),
                 *reinterpret_cast<const float4*>(px + 36), sa);
  }
  #pragma unroll
  for (int n = 0; n < 2; ++n) {
    const float* py = &y[(size_t)(j0 + n * 16 + lrow) * DD + kgrp * 8];
    b[n][0] = cvt8n(*reinterpret_cast<const float4*>(py),
                    *reinterpret_cast<const float4*>(py + 4), sb[n]);
    b[n][1] = cvt8n(*reinterpret_cast<const float4*>(py + 32),
                    *reinterpret_cast<const float4*>(py + 36), sb[n]);
  }

  // Butterfly over the kgrp bits: full norm of row (base + lrow) per lane.
  sa += __shfl_xor(sa, 16, 64);
  sa += __shfl_xor(sa, 32, 64);
  #pragma unroll
  for (int n = 0; n < 2; ++n) {
    sb[n] += __shfl_xor(sb[n], 16, 64);
    sb[n] += __shfl_xor(sb[n], 32, 64);
  }

  // Swapped-operand MFMA: D[row -> j][col -> i].
  f32x4 acc[2] = {};  // acc[n]
  #pragma unroll
  for (int ks = 0; ks < 2; ++ks)
    #pragma unroll
    for (int n = 0; n < 2; ++n)
      acc[n] = __builtin_amdgcn_mfma_f32_16x16x32_bf16(
          b[n][ks], a[ks], acc[n], 0, 0, 0);

  // Epilogue: element (n, reg r) of a lane:
  //   i = i0 + lrow (x-norm = own sa)
  //   j = j0 + n*16 + kgrp*4 + r (y-norm from lane kgrp*4+r of sb[n])
  #pragma unroll
  for (int n = 0; n < 2; ++n) {
    f32x4 res;
    float nyv, d2;
    nyv = __shfl(sb[n], kgrp * 4 + 0, 64);
    d2 = fmaf(-2.0f, acc[n][0], sa + nyv); res[0] = sqrtf(fmaxf(d2, 0.f));
    nyv = __shfl(sb[n], kgrp * 4 + 1, 64);
    d2 = fmaf(-2.0f, acc[n][1], sa + nyv); res[1] = sqrtf(fmaxf(d2, 0.f));
    nyv = __shfl(sb[n], kgrp * 4 + 2, 64);
    d2 = fmaf(-2.0f, acc[n][2], sa + nyv); res[2] = sqrtf(fmaxf(d2, 0.f));
    nyv = __shfl(sb[n], kgrp * 4 + 3, 64);
    d2 = fmaf(-2.0f, acc[n][3], sa + nyv); res[3] = sqrtf(fmaxf(d2, 0.f));
    __builtin_nontemporal_store(
        res, reinterpret_cast<f32x4*>(
            &out[(size_t)(i0 + lrow) * M + j0 + n * 16 + kgrp * 4]));
  }
}

extern "C" void kernel_launch(void* const* d_in, const int* in_sizes, int n_in,
                              void* d_out, int out_size, void* d_ws, size_t ws_size,
                              hipStream_t stream) {
  const float* x = (const float*)d_in[0];
  const float* y = (const float*)d_in[1];
  float* out = (float*)d_out;
  const int N = in_sizes[0] / DD;  // 2048
  const int M = in_sizes[1] / DD;  // 2048

  cdist_fused<<<dim3(M / 64, N / 32), dim3(256), 0, stream>>>(x, y, out, N, M);
}